// Round 11
// baseline (162.841 us; speedup 1.0000x reference)
//
#include <hip/hip_runtime.h>
#include <math.h>

#define EMBED    256
#define HIDDEN   512
#define Nn       2000
#define Ee       2000
#define BM       128     // edges per tile
#define TILES    8       // tiles per persistent block
#define NBLK     250     // 250 * 8 * 128 = 256000 edges
#define NTHREADS 512     // 8 waves = 2 edge-halves x 4 n-groups
#define FP       264     // shorts per feat row (256 + 8 pad)

typedef __attribute__((ext_vector_type(8)))  short bf16x8;
typedef __attribute__((ext_vector_type(16))) float f32x16;

static __device__ __forceinline__ short f2bf(float f) {
  unsigned u = __builtin_bit_cast(unsigned, f);
  u += 0x7fffu + ((u >> 16) & 1u);
  return (short)(u >> 16);
}

static __device__ __forceinline__ bf16x8 cvt8(float4 a, float4 b) {
  bf16x8 v;
  v[0]=f2bf(a.x); v[1]=f2bf(a.y); v[2]=f2bf(a.z); v[3]=f2bf(a.w);
  v[4]=f2bf(b.x); v[5]=f2bf(b.y); v[6]=f2bf(b.z); v[7]=f2bf(b.w);
  return v;
}

#define LBAR() do { asm volatile("s_waitcnt lgkmcnt(0)" ::: "memory"); \
                    __builtin_amdgcn_s_barrier(); \
                    asm volatile("" ::: "memory"); } while (0)

// ---- prep: W1 (513x512 f32 [k][n]) -> fragment-major W1F bf16 ----
// W1F[((tn*32 + tk)*64 + lane)*8 + q] = W1[tk*16 + (lane>>5)*8 + q][tn*32 + (lane&31)]
__global__ void w1f_kernel(const float* __restrict__ W1, short* __restrict__ W1F) {
  const int t  = blockIdx.x * 512 + threadIdx.x;   // 32768 fragment-lanes
  const int l  = t & 63;
  const int tk = (t >> 6) & 31;
  const int tn = t >> 11;
  const int n  = tn * 32 + (l & 31);
  const int k0 = tk * 16 + (l >> 5) * 8;
  bf16x8 v;
#pragma unroll
  for (int q = 0; q < 8; ++q)
    v[q] = f2bf(W1[(size_t)(k0 + q) * HIDDEN + n]);
  *(bf16x8*)(W1F + (size_t)t * 8) = v;
}

// ---- main: persistent blocks, 16 phases, et=2/nt=4 wave split ----
__global__ __launch_bounds__(NTHREADS, 2)
void edge_kernel(const float* __restrict__ emb, const float* __restrict__ locs,
                 const int* __restrict__ edges, const int* __restrict__ dbias,
                 const float* __restrict__ W1, const float* __restrict__ b1,
                 const float* __restrict__ W2, const float* __restrict__ b2,
                 const short* __restrict__ W1F, float* __restrict__ out)
{
  __shared__ short feat[2][BM][FP];               // 135,168 B
  __shared__ float b1_s[HIDDEN], w513_s[HIDDEN], w2_s[HIDDEN];  // 6 KB
  __shared__ float part_s[8][64];                 // 2 KB
  __shared__ float dist_s[2][BM];                 // 1 KB
  __shared__ int   valid_s[2][BM];                // 1 KB
  __shared__ int   ibase_s[2][BM], jbase_s[2][BM];// 2 KB

  const int tid = threadIdx.x;

  // bijective XCD-chunked swizzle over 250 blocks (xcd 0,1 -> 32; 2..7 -> 31)
  const int orig = blockIdx.x;
  const int xcd  = orig & 7;
  const int idx  = orig >> 3;
  const int sbid = (xcd < 2 ? xcd * 32 : 64 + (xcd - 2) * 31) + idx;
  const int eblk = sbid * (TILES * BM);

  b1_s[tid]   = b1[tid];
  w513_s[tid] = W1[(size_t)512 * HIDDEN + tid];
  w2_s[tid]   = W2[tid];
  const float b2s_base = b2[0] + (float)dbias[0];

  auto do_meta = [&](int T) {     // tid < BM only
    const int g  = eblk + T * BM + tid;
    const int b  = g / Ee;
    const int i0 = edges[2 * g];
    const int j0 = edges[2 * g + 1];
    valid_s[T & 1][tid] = (i0 >= 0) && (j0 >= 0);
    const int ib = b * Nn + (i0 < 0 ? 0 : i0);
    const int jb = b * Nn + (j0 < 0 ? 0 : j0);
    ibase_s[T & 1][tid] = ib;
    jbase_s[T & 1][tid] = jb;
    const float dx = locs[2 * (size_t)ib]     - locs[2 * (size_t)jb];
    const float dy = locs[2 * (size_t)ib + 1] - locs[2 * (size_t)jb + 1];
    dist_s[T & 1][tid] = sqrtf(dx * dx + dy * dy);
  };

  if (tid < BM) do_meta(0);
  LBAR();

  // staging map: 8 threads/edge-row-half; thread covers 16B chunks c = sq+8m
  const int sq = tid & 7;
  const int ehs = tid >> 3;       // 0..63 (edge within staging round)
  const int lane = tid & 63;
  const int w    = tid >> 6;      // wave 0..7
  const int eh   = w & 1;         // edge-half: edges [eh*64, +64)
  const int ng   = w >> 1;        // n-group:  n in [ng*128, +128)
  const int ln31 = lane & 31;
  const int kg   = lane >> 5;

  // ---- prologue: stage phase 0 = (tile0, emb_i) ----
#pragma unroll
  for (int r = 0; r < 2; ++r) {
    const int el = r * 64 + ehs;
    const float* src = emb + (size_t)ibase_s[0][el] * EMBED + sq * 8;
#pragma unroll
    for (int m = 0; m < 4; ++m) {
      float4 a  = *(const float4*)(src + m * 64);
      float4 b4 = *(const float4*)(src + m * 64 + 4);
      *(bf16x8*)&feat[0][el][(sq + 8 * m) * 8] = cvt8(a, b4);
    }
  }
  LBAR();

  f32x16 acc[2][4];               // [et][nt]
#pragma unroll
  for (int et = 0; et < 2; ++et)
#pragma unroll
    for (int nt = 0; nt < 4; ++nt)
#pragma unroll
      for (int q = 0; q < 16; ++q) acc[et][nt][q] = 0.f;

  // wa(nt, k16) at W1F + ((ng*4+nt)*32 + k16)*512 + lane*8
  const short* wfb = W1F + (size_t)(ng * 4 * 32) * 512 + lane * 8;

#pragma unroll 1
  for (int p = 0; p < 2 * TILES; ++p) {
    const int bb   = p & 1;
    const int nbuf = bb ^ 1;
    const int half = p & 1;            // k-half of W1 this phase covers
    const int tps  = (p + 1) >> 1;     // tile being staged
    const int sh   = (p + 1) & 1;      // 0 = emb_i, 1 = emb_j
    const bool stg = p < 2 * TILES - 1;

    bf16x8 wc[4], wn[4];
#pragma unroll
    for (int nt = 0; nt < 4; ++nt)
      wc[nt] = *(const bf16x8*)(wfb + (size_t)(nt * 32 + half * 16) * 512);

    float4 hg00, hg01, hg10, hg11;     // held gather group (16 floats)

#pragma unroll
    for (int ks = 0; ks < 16; ++ks) {
      if (ks < 15) {
#pragma unroll
        for (int nt = 0; nt < 4; ++nt)
          wn[nt] = *(const bf16x8*)(wfb + (size_t)(nt * 32 + half * 16 + ks + 1) * 512);
      }

      if (stg && (ks & 3) == 0) {      // issue gather group ks>>2
        const int g2 = ks >> 2;
        const int el = (g2 >> 1) * 64 + ehs;
        const int rb = sh ? jbase_s[tps & 1][el] : ibase_s[tps & 1][el];
        const float* src = emb + (size_t)rb * EMBED + sq * 8 + (g2 & 1) * 128;
        hg00 = *(const float4*)(src);
        hg01 = *(const float4*)(src + 4);
        hg10 = *(const float4*)(src + 64);
        hg11 = *(const float4*)(src + 68);
      }
      if (stg && (ks & 3) == 3) {      // land group ks>>2 into next buffer
        const int g2 = ks >> 2;
        const int el = (g2 >> 1) * 64 + ehs;
        const int mb = (g2 & 1) * 2;
        *(bf16x8*)&feat[nbuf][el][(sq + 8 * mb) * 8]       = cvt8(hg00, hg01);
        *(bf16x8*)&feat[nbuf][el][(sq + 8 * (mb + 1)) * 8] = cvt8(hg10, hg11);
      }
      if ((p & 1) == 0 && ks == 1 && tid < BM && (p >> 1) + 1 < TILES)
        do_meta((p >> 1) + 1);

      // fb: wave's own 64-edge half only (2 reads/ks)
      bf16x8 fb0 = *(const bf16x8*)(&feat[bb][eh * 64 + ln31][ks * 16 + kg * 8]);
      bf16x8 fb1 = *(const bf16x8*)(&feat[bb][eh * 64 + 32 + ln31][ks * 16 + kg * 8]);

      __builtin_amdgcn_s_setprio(1);
#pragma unroll
      for (int nt = 0; nt < 4; ++nt) {
        acc[0][nt] = __builtin_amdgcn_mfma_f32_32x32x16_bf16(wc[nt], fb0, acc[0][nt], 0, 0, 0);
        acc[1][nt] = __builtin_amdgcn_mfma_f32_32x32x16_bf16(wc[nt], fb1, acc[1][nt], 0, 0, 0);
      }
      __builtin_amdgcn_s_setprio(0);
#pragma unroll
      for (int nt = 0; nt < 4; ++nt) wc[nt] = wn[nt];
    }
    LBAR();   // next buffer staged + current buffer free

    if (p & 1) {
      // ---- epilogue for tile t = p>>1 ----
      const int t   = p >> 1;
      const int mb2 = t & 1;
      float dv[2], ps[2];
#pragma unroll
      for (int et = 0; et < 2; ++et) {
        dv[et] = dist_s[mb2][eh * 64 + et * 32 + ln31];
        ps[et] = 0.f;
      }
#pragma unroll
      for (int nt = 0; nt < 4; ++nt) {
#pragma unroll
        for (int r = 0; r < 16; ++r) {
          const int n = ng * 128 + nt * 32 + (r & 3) + ((r >> 2) << 3) + (kg << 2);
          const float bias = b1_s[n];
          const float wd   = w513_s[n];
          const float w2v  = w2_s[n];
#pragma unroll
          for (int et = 0; et < 2; ++et) {
            float pv = acc[et][nt][r] + bias + dv[et] * wd;
            ps[et] += fmaxf(pv, 0.f) * w2v;
          }
        }
      }
#pragma unroll
      for (int et = 0; et < 2; ++et) ps[et] += __shfl_xor(ps[et], 32, 64);
      if (lane < 32) {
#pragma unroll
        for (int et = 0; et < 2; ++et) part_s[w][et * 32 + ln31] = ps[et];
      }
      LBAR();
      if (tid < BM) {
        const int ehh = tid >> 6;
        const int es  = tid & 63;
        float s = part_s[ehh][es] + part_s[2 + ehh][es] +
                  part_s[4 + ehh][es] + part_s[6 + ehh][es];
        float logit = s + b2s_base;
        if (!valid_s[mb2][tid]) logit = -__builtin_inff();
        out[eblk + t * BM + tid] = logit;
      }
      // reset accumulators for next tile
#pragma unroll
      for (int et = 0; et < 2; ++et)
#pragma unroll
        for (int nt = 0; nt < 4; ++nt)
#pragma unroll
          for (int q = 0; q < 16; ++q) acc[et][nt][q] = 0.f;
    }
  }
}

extern "C" void kernel_launch(void* const* d_in, const int* in_sizes, int n_in,
                              void* d_out, int out_size, void* d_ws, size_t ws_size,
                              hipStream_t stream) {
  const float* emb   = (const float*)d_in[0];
  const float* locs  = (const float*)d_in[1];
  const int*   edges = (const int*)d_in[2];
  const int*   dbias = (const int*)d_in[3];
  const float* W1    = (const float*)d_in[4];
  const float* b1    = (const float*)d_in[5];
  const float* W2    = (const float*)d_in[6];
  const float* b2    = (const float*)d_in[7];
  float*       out   = (float*)d_out;
  short*       W1F   = (short*)d_ws;   // 512*512*2 = 512 KiB fragment-major

  w1f_kernel<<<dim3(64), dim3(512), 0, stream>>>(W1, W1F);
  edge_kernel<<<dim3(NBLK), dim3(NTHREADS), 0, stream>>>(
      emb, locs, edges, dbias, W1, b1, W2, b2, (const short*)W1F, out);
}